// Round 1
// baseline (2348.043 us; speedup 1.0000x reference)
//
#include <hip/hip_runtime.h>

#define DIM 128

// ---------------- CSR build ----------------

__global__ void deg_kernel(const int* __restrict__ dst, int E, int* __restrict__ cnt) {
  int e = blockIdx.x * blockDim.x + threadIdx.x;
  if (e < E) atomicAdd(&cnt[dst[e]], 1);
}

// chunk = 1024 per block (256 threads x 4). writes per-element exclusive scan
// (without inter-block offset) into excl, block sums into blksum, and dinv.
__global__ void scan1_kernel(const int* __restrict__ cnt, int n, int* __restrict__ excl,
                             int* __restrict__ blksum, float* __restrict__ dinv) {
  __shared__ int s[256];
  int t = threadIdx.x;
  int base = blockIdx.x * 1024 + t * 4;
  int v[4];
#pragma unroll
  for (int j = 0; j < 4; ++j) {
    int idx = base + j;
    v[j] = (idx < n) ? cnt[idx] : 0;
    if (idx < n) dinv[idx] = rsqrtf((float)v[j] + 1.0f);
  }
  int tsum = v[0] + v[1] + v[2] + v[3];
  s[t] = tsum;
  __syncthreads();
  for (int off = 1; off < 256; off <<= 1) {
    int x = (t >= off) ? s[t - off] : 0;
    __syncthreads();
    s[t] += x;
    __syncthreads();
  }
  int run = s[t] - tsum;  // exclusive prefix of this thread's 4 elements
#pragma unroll
  for (int j = 0; j < 4; ++j) {
    int idx = base + j;
    if (idx < n) excl[idx] = run;
    run += v[j];
  }
  if (t == 255) blksum[blockIdx.x] = s[255];
}

// exclusive scan of up to 128 block sums, in place
__global__ void scan2_kernel(int* __restrict__ blksum, int nb) {
  __shared__ int s[128];
  int t = threadIdx.x;
  int v = (t < nb) ? blksum[t] : 0;
  s[t] = v;
  __syncthreads();
  for (int off = 1; off < 128; off <<= 1) {
    int x = (t >= off) ? s[t - off] : 0;
    __syncthreads();
    s[t] += x;
    __syncthreads();
  }
  if (t < nb) blksum[t] = s[t] - v;
}

__global__ void scan3_kernel(int* __restrict__ row_ptr, int* __restrict__ cursor,
                             const int* __restrict__ blksum, int n, int E) {
  int i = blockIdx.x * blockDim.x + threadIdx.x;
  if (i < n) {
    int v = row_ptr[i] + blksum[i >> 10];
    row_ptr[i] = v;
    cursor[i] = v;
  }
  if (i == n) row_ptr[n] = E;
}

__global__ void scatter_kernel(const int* __restrict__ src, const int* __restrict__ dst,
                               int E, int* __restrict__ cursor, int* __restrict__ cols) {
  int e = blockIdx.x * blockDim.x + threadIdx.x;
  if (e < E) {
    int p = atomicAdd(&cursor[dst[e]], 1);
    cols[p] = src[e];
  }
}

// ---------------- fp32 GEMM: out[n,128] = act( (in[n,128] @ W[128,128]) * rowscale + bias ) ----------------
// rowscale == nullptr -> no per-row scale; bias == nullptr -> no bias.
// act(v) = v > 0 ? v : slope*v   (slope=1 -> identity, slope=0 -> relu)

__launch_bounds__(256, 1)
__global__ void gemm128_kernel(const float* __restrict__ in, const float* __restrict__ W,
                               float* __restrict__ out, int n,
                               const float* __restrict__ rowscale,
                               const float* __restrict__ bias, float slope) {
  __shared__ float sW[128 * 128];      // 64 KB, [k][c]
  __shared__ float sIn[64 * 132];      // 33 KB, [r][k] padded to 132
  int t = threadIdx.x;
  int row0 = blockIdx.x * 64;

  // stage W (coalesced float4)
  {
    const float4* Wv = (const float4*)W;
    float4* sWv = (float4*)sW;
#pragma unroll
    for (int i = 0; i < 16; ++i) sWv[i * 256 + t] = Wv[i * 256 + t];
  }
  // stage 64 input rows (2 contiguous rows per wave-instr)
  {
    int cpos = (t & 31) * 4;
    int rloc = t >> 5;  // 0..7
#pragma unroll
    for (int i = 0; i < 8; ++i) {
      int r = rloc + i * 8;
      int row = row0 + r;
      float4 v = make_float4(0.f, 0.f, 0.f, 0.f);
      if (row < n) v = *(const float4*)(in + (size_t)row * DIM + cpos);
      *(float4*)(&sIn[r * 132 + cpos]) = v;
    }
  }
  __syncthreads();

  int c0 = (t & 15) * 8;   // 8 output cols
  int r0 = (t >> 4) * 4;   // 4 output rows
  float acc[4][8];
#pragma unroll
  for (int i = 0; i < 4; ++i)
#pragma unroll
    for (int j = 0; j < 8; ++j) acc[i][j] = 0.f;

#pragma unroll 4
  for (int k = 0; k < 128; ++k) {
    float4 w0 = *(const float4*)&sW[k * 128 + c0];
    float4 w1 = *(const float4*)&sW[k * 128 + c0 + 4];
#pragma unroll
    for (int i = 0; i < 4; ++i) {
      float a = sIn[(r0 + i) * 132 + k];
      acc[i][0] = fmaf(a, w0.x, acc[i][0]);
      acc[i][1] = fmaf(a, w0.y, acc[i][1]);
      acc[i][2] = fmaf(a, w0.z, acc[i][2]);
      acc[i][3] = fmaf(a, w0.w, acc[i][3]);
      acc[i][4] = fmaf(a, w1.x, acc[i][4]);
      acc[i][5] = fmaf(a, w1.y, acc[i][5]);
      acc[i][6] = fmaf(a, w1.z, acc[i][6]);
      acc[i][7] = fmaf(a, w1.w, acc[i][7]);
    }
  }

#pragma unroll
  for (int i = 0; i < 4; ++i) {
    int row = row0 + r0 + i;
    if (row >= n) continue;
    float rs = rowscale ? rowscale[row] : 1.0f;
    float o[8];
#pragma unroll
    for (int j = 0; j < 8; ++j) {
      float v = acc[i][j] * rs;
      if (bias) v += bias[c0 + j];
      o[j] = (v > 0.f) ? v : v * slope;
    }
    float4* op = (float4*)(out + (size_t)row * DIM + c0);
    op[0] = make_float4(o[0], o[1], o[2], o[3]);
    op[1] = make_float4(o[4], o[5], o[6], o[7]);
  }
}

// ---------------- GCN aggregation: out[i] = act( dinv[i]*(g[i] + sum_{e->i} g[src]) + b ) ----------------
// one wave per node, float2 per lane (512B coalesced row reads)

__launch_bounds__(256)
__global__ void agg_kernel(const float* __restrict__ g, const int* __restrict__ row_ptr,
                           const int* __restrict__ cols, const float* __restrict__ dinv,
                           const float* __restrict__ bias, float* __restrict__ out,
                           int n, int relu) {
  int lane = threadIdx.x & 63;
  int node = (blockIdx.x * blockDim.x + threadIdx.x) >> 6;
  if (node >= n) return;
  int beg = row_ptr[node];
  int end = row_ptr[node + 1];
  const float2* __restrict__ g2 = (const float2*)g;
  float2 a = g2[(size_t)node * 64 + lane];  // self term
  float ax = a.x, ay = a.y;
  int e = beg;
  for (; e + 4 <= end; e += 4) {
    int s0 = cols[e + 0], s1 = cols[e + 1], s2 = cols[e + 2], s3 = cols[e + 3];
    float2 v0 = g2[(size_t)s0 * 64 + lane];
    float2 v1 = g2[(size_t)s1 * 64 + lane];
    float2 v2 = g2[(size_t)s2 * 64 + lane];
    float2 v3 = g2[(size_t)s3 * 64 + lane];
    ax += (v0.x + v1.x) + (v2.x + v3.x);
    ay += (v0.y + v1.y) + (v2.y + v3.y);
  }
  for (; e < end; ++e) {
    int s0 = cols[e];
    float2 v0 = g2[(size_t)s0 * 64 + lane];
    ax += v0.x;
    ay += v0.y;
  }
  float di = dinv[node];
  float2 bv = ((const float2*)bias)[lane];
  float ox = fmaf(di, ax, bv.x);
  float oy = fmaf(di, ay, bv.y);
  if (relu) {
    ox = fmaxf(ox, 0.f);
    oy = fmaxf(oy, 0.f);
  }
  ((float2*)out)[(size_t)node * 64 + lane] = make_float2(ox, oy);
}

// ---------------- heads ----------------

// out[i, 0:2] = act( Z[i,:] @ Wc[128,2] + bc )
__global__ void twocol_kernel(const float* __restrict__ Z, const float* __restrict__ Wc,
                              const float* __restrict__ bc, float* __restrict__ out,
                              int n, float slope) {
  int lane = threadIdx.x & 63;
  int wid = (blockIdx.x * blockDim.x + threadIdx.x) >> 6;
  int nw = (gridDim.x * blockDim.x) >> 6;
  float w00 = Wc[(2 * lane) * 2 + 0];
  float w01 = Wc[(2 * lane) * 2 + 1];
  float w10 = Wc[(2 * lane + 1) * 2 + 0];
  float w11 = Wc[(2 * lane + 1) * 2 + 1];
  float b0 = bc[0], b1 = bc[1];
  for (int i = wid; i < n; i += nw) {
    float2 z = ((const float2*)Z)[(size_t)i * 64 + lane];
    float p0 = z.x * w00 + z.y * w10;
    float p1 = z.x * w01 + z.y * w11;
#pragma unroll
    for (int off = 32; off; off >>= 1) {
      p0 += __shfl_xor(p0, off);
      p1 += __shfl_xor(p1, off);
    }
    if (lane == 0) {
      float o0 = p0 + b0, o1 = p1 + b1;
      out[2 * (size_t)i + 0] = (o0 > 0.f) ? o0 : slope * o0;
      out[2 * (size_t)i + 1] = (o1 > 0.f) ? o1 : slope * o1;
    }
  }
}

// out[t] = lrelu( Z[idx[t],:] @ w + b ), slope 0.01
__global__ void ydot_kernel(const float* __restrict__ Z, const int* __restrict__ idx,
                            const float* __restrict__ w, const float* __restrict__ b,
                            float* __restrict__ out, int T) {
  int lane = threadIdx.x & 63;
  int t = (blockIdx.x * blockDim.x + threadIdx.x) >> 6;
  if (t >= T) return;
  float2 wv = ((const float2*)w)[lane];
  int node = idx[t];
  float2 z = ((const float2*)Z)[(size_t)node * 64 + lane];
  float pp = z.x * wv.x + z.y * wv.y;
#pragma unroll
  for (int off = 32; off; off >>= 1) pp += __shfl_xor(pp, off);
  if (lane == 0) {
    float o = pp + b[0];
    out[t] = (o > 0.f) ? o : 0.01f * o;
  }
}

// ---------------- launch ----------------

extern "C" void kernel_launch(void* const* d_in, const int* in_sizes, int n_in,
                              void* d_out, int out_size, void* d_ws, size_t ws_size,
                              hipStream_t stream) {
  const int N = in_sizes[0] / DIM;
  const int E = in_sizes[1] / 2;
  const int T = in_sizes[4];

  const float* x = (const float*)d_in[0];
  const int* ei = (const int*)d_in[1];
  const float* fx = (const float*)d_in[2];
  const int* fei = (const int*)d_in[3];
  const int* treat = (const int*)d_in[4];
  const int* control = (const int*)d_in[5];
  const float* W1 = (const float*)d_in[6];
  const float* b1 = (const float*)d_in[7];
  const float* W2 = (const float*)d_in[8];
  const float* b2 = (const float*)d_in[9];
  const float* Wy1 = (const float*)d_in[10];
  const float* by1 = (const float*)d_in[11];
  const float* Wy0 = (const float*)d_in[12];
  const float* by0 = (const float*)d_in[13];
  const float* Wb = (const float*)d_in[14];
  const float* bb = (const float*)d_in[15];
  const float* Wp1 = (const float*)d_in[16];
  const float* bp1 = (const float*)d_in[17];
  const float* Wp2 = (const float*)d_in[18];
  const float* bp2 = (const float*)d_in[19];

  float* out = (float*)d_out;

  // workspace layout (~117 MB)
  char* p = (char*)d_ws;
  float* bufA = (float*)p; p += (size_t)N * DIM * sizeof(float);
  float* bufB = (float*)p; p += (size_t)N * DIM * sizeof(float);
  int* cnt = (int*)p;      p += (size_t)(N + 16) * sizeof(int);   // doubles as cursor
  int* row_ptr = (int*)p;  p += (size_t)(N + 16) * sizeof(int);
  float* dinv = (float*)p; p += (size_t)(N + 16) * sizeof(float);
  int* blksum = (int*)p;   p += 256 * sizeof(int);
  int* cols = (int*)p;     p += (size_t)E * sizeof(int);

  const int NB = (N + 1023) / 1024;  // 98 for N=100000, must be <= 128

  float* oy1 = out;                 // y1  [T]
  float* oyc0 = out + T;            // yc0 [T]
  float* oy0 = out + 2 * T;         // y0  [T]
  float* oyc1 = out + 3 * T;        // yc1 [T]
  float* ofp = out + 4 * T;               // fprob   [N,2]
  float* ofpf = out + 4 * T + 2 * N;      // fprob_f [N,2]
  float* otp = out + 4 * T + 4 * N;       // tprob   [N,2]
  float* otpf = out + 4 * T + 6 * N;      // tprob_f [N,2]

  auto run = [&](const float* X, const int* EI,
                 float* y_t, const float* Wt, const float* bt,
                 float* y_c, const float* Wc, const float* bc,
                 float* fp, float* tp) {
    const int* srcp = EI;
    const int* dstp = EI + E;
    // CSR by dst
    hipMemsetAsync(cnt, 0, (size_t)N * sizeof(int), stream);
    deg_kernel<<<(E + 255) / 256, 256, 0, stream>>>(dstp, E, cnt);
    scan1_kernel<<<NB, 256, 0, stream>>>(cnt, N, row_ptr, blksum, dinv);
    scan2_kernel<<<1, 128, 0, stream>>>(blksum, NB);
    scan3_kernel<<<(N + 256) / 256, 256, 0, stream>>>(row_ptr, cnt, blksum, N, E);
    scatter_kernel<<<(E + 255) / 256, 256, 0, stream>>>(srcp, dstp, E, cnt, cols);
    // layer 1: g = (X@W1)*dinv ; Z1 = relu(dinv*(sum g + g_self) + b1)
    gemm128_kernel<<<(N + 63) / 64, 256, 0, stream>>>(X, W1, bufA, N, dinv, nullptr, 1.0f);
    agg_kernel<<<(N + 3) / 4, 256, 0, stream>>>(bufA, row_ptr, cols, dinv, b1, bufB, N, 1);
    // layer 2
    gemm128_kernel<<<(N + 63) / 64, 256, 0, stream>>>(bufB, W2, bufA, N, dinv, nullptr, 1.0f);
    agg_kernel<<<(N + 3) / 4, 256, 0, stream>>>(bufA, row_ptr, cols, dinv, b2, bufB, N, 0);
    // bufB = Z2
    // tprob: P1 = lrelu(Z2@Wp1 + bp1); tp = lrelu(P1@Wp2 + bp2)
    gemm128_kernel<<<(N + 63) / 64, 256, 0, stream>>>(bufB, Wp1, bufA, N, nullptr, bp1, 0.01f);
    twocol_kernel<<<2048, 256, 0, stream>>>(bufA, Wp2, bp2, tp, N, 0.01f);
    // fprob (grl = identity in fwd)
    twocol_kernel<<<2048, 256, 0, stream>>>(bufB, Wb, bb, fp, N, 1.0f);
    // y heads
    ydot_kernel<<<(T + 3) / 4, 256, 0, stream>>>(bufB, treat, Wt, bt, y_t, T);
    ydot_kernel<<<(T + 3) / 4, 256, 0, stream>>>(bufB, control, Wc, bc, y_c, T);
  };

  // real graph: y1(treat,Wy1), y0(control,Wy0), fprob, tprob
  run(x, ei, oy1, Wy1, by1, oy0, Wy0, by0, ofp, otp);
  // fake graph: yc0(treat,Wy0), yc1(control,Wy1), fprob_f, tprob_f
  run(fx, fei, oyc0, Wy0, by0, oyc1, Wy1, by1, ofpf, otpf);
}

// Round 2
// 2344.877 us; speedup vs baseline: 1.0014x; 1.0014x over previous
//
#include <hip/hip_runtime.h>

#define DIM 128
#define BSH 5                 // bucket = 32 consecutive node ids
#define BSZ 32
#define CPAD 16               // one counter per 64B line

// ---------------- bucketed CSR build ----------------

__global__ void bhist_kernel(const int* __restrict__ dst, int E, int* __restrict__ bhist) {
  int e = blockIdx.x * blockDim.x + threadIdx.x;
  if (e < E) atomicAdd(&bhist[(dst[e] >> BSH) * CPAD], 1);
}

// single-block exclusive scan over nb (<=4096) bucket counts; writes boff[0..nb] and bcur
__global__ void bscan_kernel(const int* __restrict__ bhist, int nb, int E,
                             int* __restrict__ boff, int* __restrict__ bcur) {
  __shared__ int s[256];
  int t = threadIdx.x;
  int v[16];
  int tsum = 0;
#pragma unroll
  for (int j = 0; j < 16; ++j) {
    int idx = t * 16 + j;
    v[j] = (idx < nb) ? bhist[idx * CPAD] : 0;
    tsum += v[j];
  }
  s[t] = tsum;
  __syncthreads();
  for (int off = 1; off < 256; off <<= 1) {
    int x = (t >= off) ? s[t - off] : 0;
    __syncthreads();
    s[t] += x;
    __syncthreads();
  }
  int run = s[t] - tsum;
#pragma unroll
  for (int j = 0; j < 16; ++j) {
    int idx = t * 16 + j;
    if (idx < nb) {
      boff[idx] = run;
      bcur[idx * CPAD] = run;
    }
    run += v[j];
  }
  if (t == 255) boff[nb] = E;
}

__global__ void bscatter_kernel(const int* __restrict__ src, const int* __restrict__ dst,
                                int E, int* __restrict__ bcur, int2* __restrict__ tmp) {
  int e = blockIdx.x * blockDim.x + threadIdx.x;
  if (e < E) {
    int d = dst[e];
    int p = atomicAdd(&bcur[(d >> BSH) * CPAD], 1);
    tmp[p] = make_int2(src[e], d);
  }
}

// one block per bucket: local degree hist -> row_ptr/dinv, then scatter src into cols
__global__ void bbuild_kernel(const int2* __restrict__ tmp, const int* __restrict__ boff,
                              int nb, int N, int E, int* __restrict__ row_ptr,
                              int* __restrict__ cols, float* __restrict__ dinv) {
  __shared__ int ldeg[BSZ];
  __shared__ int lcur[BSZ];
  int b = blockIdx.x;
  int node0 = b << BSH;
  int t = threadIdx.x;
  int beg = boff[b], end = boff[b + 1];
  if (t < BSZ) ldeg[t] = 0;
  __syncthreads();
  for (int i = beg + t; i < end; i += blockDim.x) {
    atomicAdd(&ldeg[tmp[i].y - node0], 1);
  }
  __syncthreads();
  if (t == 0) {
    int run = beg;
    int nn = min(BSZ, N - node0);
    for (int j = 0; j < nn; ++j) {
      lcur[j] = run;
      row_ptr[node0 + j] = run;
      dinv[node0 + j] = rsqrtf((float)ldeg[j] + 1.0f);
      run += ldeg[j];
    }
    if (b == nb - 1) row_ptr[N] = E;
  }
  __syncthreads();
  for (int i = beg + t; i < end; i += blockDim.x) {
    int2 eg = tmp[i];
    int p = atomicAdd(&lcur[eg.y - node0], 1);
    cols[p] = eg.x;
  }
}

// ---------------- fp32 GEMM: out[n,128] = act( (in[n,128] @ W[128,128]) * rowscale + bias ) ----------------

__launch_bounds__(256, 1)
__global__ void gemm128_kernel(const float* __restrict__ in, const float* __restrict__ W,
                               float* __restrict__ out, int n,
                               const float* __restrict__ rowscale,
                               const float* __restrict__ bias, float slope) {
  __shared__ float sW[128 * 128];      // 64 KB, [k][c]
  __shared__ float sIn[64 * 132];      // 33 KB, [r][k] padded to 132
  int t = threadIdx.x;
  int row0 = blockIdx.x * 64;

  {
    const float4* Wv = (const float4*)W;
    float4* sWv = (float4*)sW;
#pragma unroll
    for (int i = 0; i < 16; ++i) sWv[i * 256 + t] = Wv[i * 256 + t];
  }
  {
    int cpos = (t & 31) * 4;
    int rloc = t >> 5;
#pragma unroll
    for (int i = 0; i < 8; ++i) {
      int r = rloc + i * 8;
      int row = row0 + r;
      float4 v = make_float4(0.f, 0.f, 0.f, 0.f);
      if (row < n) v = *(const float4*)(in + (size_t)row * DIM + cpos);
      *(float4*)(&sIn[r * 132 + cpos]) = v;
    }
  }
  __syncthreads();

  int c0 = (t & 15) * 8;
  int r0 = (t >> 4) * 4;
  float acc[4][8];
#pragma unroll
  for (int i = 0; i < 4; ++i)
#pragma unroll
    for (int j = 0; j < 8; ++j) acc[i][j] = 0.f;

#pragma unroll 4
  for (int k = 0; k < 128; ++k) {
    float4 w0 = *(const float4*)&sW[k * 128 + c0];
    float4 w1 = *(const float4*)&sW[k * 128 + c0 + 4];
#pragma unroll
    for (int i = 0; i < 4; ++i) {
      float a = sIn[(r0 + i) * 132 + k];
      acc[i][0] = fmaf(a, w0.x, acc[i][0]);
      acc[i][1] = fmaf(a, w0.y, acc[i][1]);
      acc[i][2] = fmaf(a, w0.z, acc[i][2]);
      acc[i][3] = fmaf(a, w0.w, acc[i][3]);
      acc[i][4] = fmaf(a, w1.x, acc[i][4]);
      acc[i][5] = fmaf(a, w1.y, acc[i][5]);
      acc[i][6] = fmaf(a, w1.z, acc[i][6]);
      acc[i][7] = fmaf(a, w1.w, acc[i][7]);
    }
  }

#pragma unroll
  for (int i = 0; i < 4; ++i) {
    int row = row0 + r0 + i;
    if (row >= n) continue;
    float rs = rowscale ? rowscale[row] : 1.0f;
    float o[8];
#pragma unroll
    for (int j = 0; j < 8; ++j) {
      float v = acc[i][j] * rs;
      if (bias) v += bias[c0 + j];
      o[j] = (v > 0.f) ? v : v * slope;
    }
    float4* op = (float4*)(out + (size_t)row * DIM + c0);
    op[0] = make_float4(o[0], o[1], o[2], o[3]);
    op[1] = make_float4(o[4], o[5], o[6], o[7]);
  }
}

// ---------------- GCN aggregation ----------------

__launch_bounds__(256)
__global__ void agg_kernel(const float* __restrict__ g, const int* __restrict__ row_ptr,
                           const int* __restrict__ cols, const float* __restrict__ dinv,
                           const float* __restrict__ bias, float* __restrict__ out,
                           int n, int relu) {
  int lane = threadIdx.x & 63;
  int node = (blockIdx.x * blockDim.x + threadIdx.x) >> 6;
  if (node >= n) return;
  int beg = row_ptr[node];
  int end = row_ptr[node + 1];
  const float2* __restrict__ g2 = (const float2*)g;
  float2 a = g2[(size_t)node * 64 + lane];
  float ax = a.x, ay = a.y;
  int e = beg;
  for (; e + 4 <= end; e += 4) {
    int s0 = cols[e + 0], s1 = cols[e + 1], s2 = cols[e + 2], s3 = cols[e + 3];
    float2 v0 = g2[(size_t)s0 * 64 + lane];
    float2 v1 = g2[(size_t)s1 * 64 + lane];
    float2 v2 = g2[(size_t)s2 * 64 + lane];
    float2 v3 = g2[(size_t)s3 * 64 + lane];
    ax += (v0.x + v1.x) + (v2.x + v3.x);
    ay += (v0.y + v1.y) + (v2.y + v3.y);
  }
  for (; e < end; ++e) {
    int s0 = cols[e];
    float2 v0 = g2[(size_t)s0 * 64 + lane];
    ax += v0.x;
    ay += v0.y;
  }
  float di = dinv[node];
  float2 bv = ((const float2*)bias)[lane];
  float ox = fmaf(di, ax, bv.x);
  float oy = fmaf(di, ay, bv.y);
  if (relu) {
    ox = fmaxf(ox, 0.f);
    oy = fmaxf(oy, 0.f);
  }
  ((float2*)out)[(size_t)node * 64 + lane] = make_float2(ox, oy);
}

// ---------------- heads ----------------

__global__ void twocol_kernel(const float* __restrict__ Z, const float* __restrict__ Wc,
                              const float* __restrict__ bc, float* __restrict__ out,
                              int n, float slope) {
  int lane = threadIdx.x & 63;
  int wid = (blockIdx.x * blockDim.x + threadIdx.x) >> 6;
  int nw = (gridDim.x * blockDim.x) >> 6;
  float w00 = Wc[(2 * lane) * 2 + 0];
  float w01 = Wc[(2 * lane) * 2 + 1];
  float w10 = Wc[(2 * lane + 1) * 2 + 0];
  float w11 = Wc[(2 * lane + 1) * 2 + 1];
  float b0 = bc[0], b1 = bc[1];
  for (int i = wid; i < n; i += nw) {
    float2 z = ((const float2*)Z)[(size_t)i * 64 + lane];
    float p0 = z.x * w00 + z.y * w10;
    float p1 = z.x * w01 + z.y * w11;
#pragma unroll
    for (int off = 32; off; off >>= 1) {
      p0 += __shfl_xor(p0, off);
      p1 += __shfl_xor(p1, off);
    }
    if (lane == 0) {
      float o0 = p0 + b0, o1 = p1 + b1;
      out[2 * (size_t)i + 0] = (o0 > 0.f) ? o0 : slope * o0;
      out[2 * (size_t)i + 1] = (o1 > 0.f) ? o1 : slope * o1;
    }
  }
}

__global__ void ydot_kernel(const float* __restrict__ Z, const int* __restrict__ idx,
                            const float* __restrict__ w, const float* __restrict__ b,
                            float* __restrict__ out, int T) {
  int lane = threadIdx.x & 63;
  int t = (blockIdx.x * blockDim.x + threadIdx.x) >> 6;
  if (t >= T) return;
  float2 wv = ((const float2*)w)[lane];
  int node = idx[t];
  float2 z = ((const float2*)Z)[(size_t)node * 64 + lane];
  float pp = z.x * wv.x + z.y * wv.y;
#pragma unroll
  for (int off = 32; off; off >>= 1) pp += __shfl_xor(pp, off);
  if (lane == 0) {
    float o = pp + b[0];
    out[t] = (o > 0.f) ? o : 0.01f * o;
  }
}

// ---------------- launch ----------------

extern "C" void kernel_launch(void* const* d_in, const int* in_sizes, int n_in,
                              void* d_out, int out_size, void* d_ws, size_t ws_size,
                              hipStream_t stream) {
  const int N = in_sizes[0] / DIM;
  const int E = in_sizes[1] / 2;
  const int T = in_sizes[4];
  const int nb = (N + BSZ - 1) >> BSH;

  const float* x = (const float*)d_in[0];
  const int* ei = (const int*)d_in[1];
  const float* fx = (const float*)d_in[2];
  const int* fei = (const int*)d_in[3];
  const int* treat = (const int*)d_in[4];
  const int* control = (const int*)d_in[5];
  const float* W1 = (const float*)d_in[6];
  const float* b1 = (const float*)d_in[7];
  const float* W2 = (const float*)d_in[8];
  const float* b2 = (const float*)d_in[9];
  const float* Wy1 = (const float*)d_in[10];
  const float* by1 = (const float*)d_in[11];
  const float* Wy0 = (const float*)d_in[12];
  const float* by0 = (const float*)d_in[13];
  const float* Wb = (const float*)d_in[14];
  const float* bb = (const float*)d_in[15];
  const float* Wp1 = (const float*)d_in[16];
  const float* bp1 = (const float*)d_in[17];
  const float* Wp2 = (const float*)d_in[18];
  const float* bp2 = (const float*)d_in[19];

  float* out = (float*)d_out;

  // workspace layout
  char* p = (char*)d_ws;
  float* bufA = (float*)p; p += (size_t)N * DIM * sizeof(float);
  float* bufB = (float*)p; p += (size_t)N * DIM * sizeof(float);
  int* row_ptr = (int*)p;  p += (size_t)(N + 16) * sizeof(int);
  float* dinv = (float*)p; p += (size_t)(N + 16) * sizeof(float);
  int* cols = (int*)p;     p += (size_t)E * sizeof(int);
  int* bhist = (int*)p;    p += (size_t)(nb + 1) * CPAD * sizeof(int);
  int* bcur = (int*)p;     p += (size_t)(nb + 1) * CPAD * sizeof(int);
  int* boff = (int*)p;     p += (size_t)(nb + 2) * sizeof(int);
  int2* tmp = (int2*)bufA;  // bufA is free during CSR build

  float* oy1 = out;
  float* oyc0 = out + T;
  float* oy0 = out + 2 * T;
  float* oyc1 = out + 3 * T;
  float* ofp = out + 4 * T;
  float* ofpf = out + 4 * T + 2 * N;
  float* otp = out + 4 * T + 4 * N;
  float* otpf = out + 4 * T + 6 * N;

  auto run = [&](const float* X, const int* EI,
                 float* y_t, const float* Wt, const float* bt,
                 float* y_c, const float* Wc, const float* bc,
                 float* fp, float* tp) {
    const int* srcp = EI;
    const int* dstp = EI + E;
    // bucketed CSR build (tmp aliases bufA)
    hipMemsetAsync(bhist, 0, (size_t)nb * CPAD * sizeof(int), stream);
    bhist_kernel<<<(E + 255) / 256, 256, 0, stream>>>(dstp, E, bhist);
    bscan_kernel<<<1, 256, 0, stream>>>(bhist, nb, E, boff, bcur);
    bscatter_kernel<<<(E + 255) / 256, 256, 0, stream>>>(srcp, dstp, E, bcur, tmp);
    bbuild_kernel<<<nb, 256, 0, stream>>>(tmp, boff, nb, N, E, row_ptr, cols, dinv);
    // layer 1: g = (X@W1)*dinv ; Z1 = relu(dinv*(sum g + g_self) + b1)
    gemm128_kernel<<<(N + 63) / 64, 256, 0, stream>>>(X, W1, bufA, N, dinv, nullptr, 1.0f);
    agg_kernel<<<(N + 3) / 4, 256, 0, stream>>>(bufA, row_ptr, cols, dinv, b1, bufB, N, 1);
    // layer 2
    gemm128_kernel<<<(N + 63) / 64, 256, 0, stream>>>(bufB, W2, bufA, N, dinv, nullptr, 1.0f);
    agg_kernel<<<(N + 3) / 4, 256, 0, stream>>>(bufA, row_ptr, cols, dinv, b2, bufB, N, 0);
    // bufB = Z2
    gemm128_kernel<<<(N + 63) / 64, 256, 0, stream>>>(bufB, Wp1, bufA, N, nullptr, bp1, 0.01f);
    twocol_kernel<<<2048, 256, 0, stream>>>(bufA, Wp2, bp2, tp, N, 0.01f);
    twocol_kernel<<<2048, 256, 0, stream>>>(bufB, Wb, bb, fp, N, 1.0f);
    ydot_kernel<<<(T + 3) / 4, 256, 0, stream>>>(bufB, treat, Wt, bt, y_t, T);
    ydot_kernel<<<(T + 3) / 4, 256, 0, stream>>>(bufB, control, Wc, bc, y_c, T);
  };

  run(x, ei, oy1, Wy1, by1, oy0, Wy0, by0, ofp, otp);
  run(fx, fei, oyc0, Wy0, by0, oyc1, Wy1, by1, ofpf, otpf);
}

// Round 3
// 2213.405 us; speedup vs baseline: 1.0608x; 1.0594x over previous
//
#include <hip/hip_runtime.h>

#define DIM 128
#define BSH 5                 // bucket = 32 consecutive node ids
#define BSZ 32
#define NG 8                  // edge groups ~ XCDs (blockIdx & 7)

// ---------------- bucketed CSR build (XCD-partitioned scatter) ----------------

// per-group histogram, layout bhist[g*nb + b] (g-major: no cross-XCD line sharing)
__global__ void bhist_kernel(const int* __restrict__ dst, int E, int nb,
                             int* __restrict__ bhist) {
  int e = blockIdx.x * blockDim.x + threadIdx.x;
  int g = blockIdx.x & (NG - 1);
  if (e < E) atomicAdd(&bhist[g * nb + (dst[e] >> BSH)], 1);
}

// single-block exclusive scan in order f = b*NG + g over bhist[g*nb+b].
// writes bcur[g*nb+b] (scatter cursors) and boff[b] (bucket starts).
__global__ void bscan_kernel(const int* __restrict__ bhist, int nb, int E,
                             int* __restrict__ boff, int* __restrict__ bcur) {
  __shared__ int s[256];
  int t = threadIdx.x;
  int total = nb * NG;
  int ch = (total + 255) / 256;
  int i0 = t * ch;
  int i1 = min(i0 + ch, total);
  int tsum = 0;
  for (int i = i0; i < i1; ++i) {
    int g = i & (NG - 1), b = i >> 3;
    tsum += bhist[g * nb + b];
  }
  s[t] = tsum;
  __syncthreads();
  for (int off = 1; off < 256; off <<= 1) {
    int x = (t >= off) ? s[t - off] : 0;
    __syncthreads();
    s[t] += x;
    __syncthreads();
  }
  int run = s[t] - tsum;
  for (int i = i0; i < i1; ++i) {
    int g = i & (NG - 1), b = i >> 3;
    if (g == 0) boff[b] = run;
    bcur[g * nb + b] = run;
    run += bhist[g * nb + b];
  }
  if (t == 255) boff[nb] = E;
}

// scatter edges into tmp; each (g,b) segment written only by blocks with blockIdx&7==g
__global__ void bscatter_kernel(const int* __restrict__ src, const int* __restrict__ dst,
                                int E, int nb, int* __restrict__ bcur,
                                int2* __restrict__ tmp) {
  int e = blockIdx.x * blockDim.x + threadIdx.x;
  int g = blockIdx.x & (NG - 1);
  if (e < E) {
    int d = dst[e];
    int p = atomicAdd(&bcur[g * nb + (d >> BSH)], 1);
    tmp[p] = make_int2(src[e], d);
  }
}

// one block per bucket: local degree hist -> row_ptr/dinv, then scatter src into cols
__global__ void bbuild_kernel(const int2* __restrict__ tmp, const int* __restrict__ boff,
                              int nb, int N, int E, int* __restrict__ row_ptr,
                              int* __restrict__ cols, float* __restrict__ dinv) {
  __shared__ int ldeg[BSZ];
  __shared__ int lcur[BSZ];
  int b = blockIdx.x;
  int node0 = b << BSH;
  int t = threadIdx.x;
  int beg = boff[b], end = boff[b + 1];
  if (t < BSZ) ldeg[t] = 0;
  __syncthreads();
  for (int i = beg + t; i < end; i += blockDim.x) {
    atomicAdd(&ldeg[tmp[i].y - node0], 1);
  }
  __syncthreads();
  if (t == 0) {
    int run = beg;
    int nn = min(BSZ, N - node0);
    for (int j = 0; j < nn; ++j) {
      lcur[j] = run;
      row_ptr[node0 + j] = run;
      dinv[node0 + j] = rsqrtf((float)ldeg[j] + 1.0f);
      run += ldeg[j];
    }
    if (b == nb - 1) row_ptr[N] = E;
  }
  __syncthreads();
  for (int i = beg + t; i < end; i += blockDim.x) {
    int2 eg = tmp[i];
    int p = atomicAdd(&lcur[eg.y - node0], 1);
    cols[p] = eg.x;
  }
}

// ---------------- fp32 GEMM: out[n,128] = act( (in[n,128] @ W[128,128]) * rowscale + bias ) ----------------

__launch_bounds__(256, 1)
__global__ void gemm128_kernel(const float* __restrict__ in, const float* __restrict__ W,
                               float* __restrict__ out, int n,
                               const float* __restrict__ rowscale,
                               const float* __restrict__ bias, float slope) {
  __shared__ float sW[128 * 128];      // 64 KB, [k][c]
  __shared__ float sIn[64 * 132];      // 33 KB, [r][k] padded to 132
  int t = threadIdx.x;
  int row0 = blockIdx.x * 64;

  {
    const float4* Wv = (const float4*)W;
    float4* sWv = (float4*)sW;
#pragma unroll
    for (int i = 0; i < 16; ++i) sWv[i * 256 + t] = Wv[i * 256 + t];
  }
  {
    int cpos = (t & 31) * 4;
    int rloc = t >> 5;
#pragma unroll
    for (int i = 0; i < 8; ++i) {
      int r = rloc + i * 8;
      int row = row0 + r;
      float4 v = make_float4(0.f, 0.f, 0.f, 0.f);
      if (row < n) v = *(const float4*)(in + (size_t)row * DIM + cpos);
      *(float4*)(&sIn[r * 132 + cpos]) = v;
    }
  }
  __syncthreads();

  int c0 = (t & 15) * 8;
  int r0 = (t >> 4) * 4;
  float acc[4][8];
#pragma unroll
  for (int i = 0; i < 4; ++i)
#pragma unroll
    for (int j = 0; j < 8; ++j) acc[i][j] = 0.f;

#pragma unroll 4
  for (int k = 0; k < 128; ++k) {
    float4 w0 = *(const float4*)&sW[k * 128 + c0];
    float4 w1 = *(const float4*)&sW[k * 128 + c0 + 4];
#pragma unroll
    for (int i = 0; i < 4; ++i) {
      float a = sIn[(r0 + i) * 132 + k];
      acc[i][0] = fmaf(a, w0.x, acc[i][0]);
      acc[i][1] = fmaf(a, w0.y, acc[i][1]);
      acc[i][2] = fmaf(a, w0.z, acc[i][2]);
      acc[i][3] = fmaf(a, w0.w, acc[i][3]);
      acc[i][4] = fmaf(a, w1.x, acc[i][4]);
      acc[i][5] = fmaf(a, w1.y, acc[i][5]);
      acc[i][6] = fmaf(a, w1.z, acc[i][6]);
      acc[i][7] = fmaf(a, w1.w, acc[i][7]);
    }
  }

#pragma unroll
  for (int i = 0; i < 4; ++i) {
    int row = row0 + r0 + i;
    if (row >= n) continue;
    float rs = rowscale ? rowscale[row] : 1.0f;
    float o[8];
#pragma unroll
    for (int j = 0; j < 8; ++j) {
      float v = acc[i][j] * rs;
      if (bias) v += bias[c0 + j];
      o[j] = (v > 0.f) ? v : v * slope;
    }
    float4* op = (float4*)(out + (size_t)row * DIM + c0);
    op[0] = make_float4(o[0], o[1], o[2], o[3]);
    op[1] = make_float4(o[4], o[5], o[6], o[7]);
  }
}

// ---------------- GCN aggregation ----------------

__launch_bounds__(256)
__global__ void agg_kernel(const float* __restrict__ g, const int* __restrict__ row_ptr,
                           const int* __restrict__ cols, const float* __restrict__ dinv,
                           const float* __restrict__ bias, float* __restrict__ out,
                           int n, int relu) {
  int lane = threadIdx.x & 63;
  int node = (blockIdx.x * blockDim.x + threadIdx.x) >> 6;
  if (node >= n) return;
  int beg = row_ptr[node];
  int end = row_ptr[node + 1];
  const float2* __restrict__ g2 = (const float2*)g;
  float2 a = g2[(size_t)node * 64 + lane];
  float ax = a.x, ay = a.y;
  int e = beg;
  for (; e + 4 <= end; e += 4) {
    int s0 = cols[e + 0], s1 = cols[e + 1], s2 = cols[e + 2], s3 = cols[e + 3];
    float2 v0 = g2[(size_t)s0 * 64 + lane];
    float2 v1 = g2[(size_t)s1 * 64 + lane];
    float2 v2 = g2[(size_t)s2 * 64 + lane];
    float2 v3 = g2[(size_t)s3 * 64 + lane];
    ax += (v0.x + v1.x) + (v2.x + v3.x);
    ay += (v0.y + v1.y) + (v2.y + v3.y);
  }
  for (; e < end; ++e) {
    int s0 = cols[e];
    float2 v0 = g2[(size_t)s0 * 64 + lane];
    ax += v0.x;
    ay += v0.y;
  }
  float di = dinv[node];
  float2 bv = ((const float2*)bias)[lane];
  float ox = fmaf(di, ax, bv.x);
  float oy = fmaf(di, ay, bv.y);
  if (relu) {
    ox = fmaxf(ox, 0.f);
    oy = fmaxf(oy, 0.f);
  }
  ((float2*)out)[(size_t)node * 64 + lane] = make_float2(ox, oy);
}

// ---------------- heads ----------------

__global__ void twocol_kernel(const float* __restrict__ Z, const float* __restrict__ Wc,
                              const float* __restrict__ bc, float* __restrict__ out,
                              int n, float slope) {
  int lane = threadIdx.x & 63;
  int wid = (blockIdx.x * blockDim.x + threadIdx.x) >> 6;
  int nw = (gridDim.x * blockDim.x) >> 6;
  float w00 = Wc[(2 * lane) * 2 + 0];
  float w01 = Wc[(2 * lane) * 2 + 1];
  float w10 = Wc[(2 * lane + 1) * 2 + 0];
  float w11 = Wc[(2 * lane + 1) * 2 + 1];
  float b0 = bc[0], b1 = bc[1];
  for (int i = wid; i < n; i += nw) {
    float2 z = ((const float2*)Z)[(size_t)i * 64 + lane];
    float p0 = z.x * w00 + z.y * w10;
    float p1 = z.x * w01 + z.y * w11;
#pragma unroll
    for (int off = 32; off; off >>= 1) {
      p0 += __shfl_xor(p0, off);
      p1 += __shfl_xor(p1, off);
    }
    if (lane == 0) {
      float o0 = p0 + b0, o1 = p1 + b1;
      out[2 * (size_t)i + 0] = (o0 > 0.f) ? o0 : slope * o0;
      out[2 * (size_t)i + 1] = (o1 > 0.f) ? o1 : slope * o1;
    }
  }
}

__global__ void ydot_kernel(const float* __restrict__ Z, const int* __restrict__ idx,
                            const float* __restrict__ w, const float* __restrict__ b,
                            float* __restrict__ out, int T) {
  int lane = threadIdx.x & 63;
  int t = (blockIdx.x * blockDim.x + threadIdx.x) >> 6;
  if (t >= T) return;
  float2 wv = ((const float2*)w)[lane];
  int node = idx[t];
  float2 z = ((const float2*)Z)[(size_t)node * 64 + lane];
  float pp = z.x * wv.x + z.y * wv.y;
#pragma unroll
  for (int off = 32; off; off >>= 1) pp += __shfl_xor(pp, off);
  if (lane == 0) {
    float o = pp + b[0];
    out[t] = (o > 0.f) ? o : 0.01f * o;
  }
}

// ---------------- launch ----------------

extern "C" void kernel_launch(void* const* d_in, const int* in_sizes, int n_in,
                              void* d_out, int out_size, void* d_ws, size_t ws_size,
                              hipStream_t stream) {
  const int N = in_sizes[0] / DIM;
  const int E = in_sizes[1] / 2;
  const int T = in_sizes[4];
  const int nb = (N + BSZ - 1) >> BSH;

  const float* x = (const float*)d_in[0];
  const int* ei = (const int*)d_in[1];
  const float* fx = (const float*)d_in[2];
  const int* fei = (const int*)d_in[3];
  const int* treat = (const int*)d_in[4];
  const int* control = (const int*)d_in[5];
  const float* W1 = (const float*)d_in[6];
  const float* b1 = (const float*)d_in[7];
  const float* W2 = (const float*)d_in[8];
  const float* b2 = (const float*)d_in[9];
  const float* Wy1 = (const float*)d_in[10];
  const float* by1 = (const float*)d_in[11];
  const float* Wy0 = (const float*)d_in[12];
  const float* by0 = (const float*)d_in[13];
  const float* Wb = (const float*)d_in[14];
  const float* bb = (const float*)d_in[15];
  const float* Wp1 = (const float*)d_in[16];
  const float* bp1 = (const float*)d_in[17];
  const float* Wp2 = (const float*)d_in[18];
  const float* bp2 = (const float*)d_in[19];

  float* out = (float*)d_out;

  // workspace layout
  char* p = (char*)d_ws;
  float* bufA = (float*)p; p += (size_t)N * DIM * sizeof(float);
  float* bufB = (float*)p; p += (size_t)N * DIM * sizeof(float);
  int* row_ptr = (int*)p;  p += (size_t)(N + 16) * sizeof(int);
  float* dinv = (float*)p; p += (size_t)(N + 16) * sizeof(float);
  int* cols = (int*)p;     p += (size_t)E * sizeof(int);
  int* bhist = (int*)p;    p += (size_t)nb * NG * sizeof(int);
  int* bcur = (int*)p;     p += (size_t)nb * NG * sizeof(int);
  int* boff = (int*)p;     p += (size_t)(nb + 2) * sizeof(int);
  int2* tmp = (int2*)bufA;  // bufA is free during CSR build

  float* oy1 = out;
  float* oyc0 = out + T;
  float* oy0 = out + 2 * T;
  float* oyc1 = out + 3 * T;
  float* ofp = out + 4 * T;
  float* ofpf = out + 4 * T + 2 * N;
  float* otp = out + 4 * T + 4 * N;
  float* otpf = out + 4 * T + 6 * N;

  auto run = [&](const float* X, const int* EI,
                 float* y_t, const float* Wt, const float* bt,
                 float* y_c, const float* Wc, const float* bc,
                 float* fp, float* tp) {
    const int* srcp = EI;
    const int* dstp = EI + E;
    // XCD-partitioned bucketed CSR build (tmp aliases bufA)
    hipMemsetAsync(bhist, 0, (size_t)nb * NG * sizeof(int), stream);
    bhist_kernel<<<(E + 255) / 256, 256, 0, stream>>>(dstp, E, nb, bhist);
    bscan_kernel<<<1, 256, 0, stream>>>(bhist, nb, E, boff, bcur);
    bscatter_kernel<<<(E + 255) / 256, 256, 0, stream>>>(srcp, dstp, E, nb, bcur, tmp);
    bbuild_kernel<<<nb, 256, 0, stream>>>(tmp, boff, nb, N, E, row_ptr, cols, dinv);
    // layer 1: g = (X@W1)*dinv ; Z1 = relu(dinv*(sum g + g_self) + b1)
    gemm128_kernel<<<(N + 63) / 64, 256, 0, stream>>>(X, W1, bufA, N, dinv, nullptr, 1.0f);
    agg_kernel<<<(N + 3) / 4, 256, 0, stream>>>(bufA, row_ptr, cols, dinv, b1, bufB, N, 1);
    // layer 2
    gemm128_kernel<<<(N + 63) / 64, 256, 0, stream>>>(bufB, W2, bufA, N, dinv, nullptr, 1.0f);
    agg_kernel<<<(N + 3) / 4, 256, 0, stream>>>(bufA, row_ptr, cols, dinv, b2, bufB, N, 0);
    // bufB = Z2
    gemm128_kernel<<<(N + 63) / 64, 256, 0, stream>>>(bufB, Wp1, bufA, N, nullptr, bp1, 0.01f);
    twocol_kernel<<<2048, 256, 0, stream>>>(bufA, Wp2, bp2, tp, N, 0.01f);
    twocol_kernel<<<2048, 256, 0, stream>>>(bufB, Wb, bb, fp, N, 1.0f);
    ydot_kernel<<<(T + 3) / 4, 256, 0, stream>>>(bufB, treat, Wt, bt, y_t, T);
    ydot_kernel<<<(T + 3) / 4, 256, 0, stream>>>(bufB, control, Wc, bc, y_c, T);
  };

  run(x, ei, oy1, Wy1, by1, oy0, Wy0, by0, ofp, otp);
  run(fx, fei, oyc0, Wy0, by0, oyc1, Wy1, by1, ofpf, otpf);
}

// Round 4
// 1459.989 us; speedup vs baseline: 1.6083x; 1.5160x over previous
//
#include <hip/hip_runtime.h>

#define DIM 128
#define BSH 5                 // bucket = 32 consecutive node ids
#define BSZ 32
#define NG 8                  // edge groups ~ XCDs (blockIdx & 7)

typedef unsigned int uint32;
typedef unsigned short ushort16;
typedef __attribute__((ext_vector_type(8))) short short8;
typedef __attribute__((ext_vector_type(4))) float f32x4;

__device__ __forceinline__ uint32 bf16_rtne(float f) {
  uint32 u = __float_as_uint(f);
  return (u + 0x7FFFu + ((u >> 16) & 1u)) >> 16;
}
__device__ __forceinline__ float bf16_to_f(uint32 h) { return __uint_as_float(h << 16); }
__device__ __forceinline__ void unpack2(uint32 u, float& x, float& y) {
  x = __uint_as_float(u << 16);
  y = __uint_as_float(u & 0xFFFF0000u);
}

// ---------------- bucketed CSR build (XCD-partitioned scatter) ----------------

__global__ void bhist_kernel(const int* __restrict__ dst, int E, int nb,
                             int* __restrict__ bhist) {
  int e = blockIdx.x * blockDim.x + threadIdx.x;
  int g = blockIdx.x & (NG - 1);
  if (e < E) atomicAdd(&bhist[g * nb + (dst[e] >> BSH)], 1);
}

__global__ void bscan_kernel(const int* __restrict__ bhist, int nb, int E,
                             int* __restrict__ boff, int* __restrict__ bcur) {
  __shared__ int s[256];
  int t = threadIdx.x;
  int total = nb * NG;
  int ch = (total + 255) / 256;
  int i0 = t * ch;
  int i1 = min(i0 + ch, total);
  int tsum = 0;
  for (int i = i0; i < i1; ++i) {
    int g = i & (NG - 1), b = i >> 3;
    tsum += bhist[g * nb + b];
  }
  s[t] = tsum;
  __syncthreads();
  for (int off = 1; off < 256; off <<= 1) {
    int x = (t >= off) ? s[t - off] : 0;
    __syncthreads();
    s[t] += x;
    __syncthreads();
  }
  int run = s[t] - tsum;
  for (int i = i0; i < i1; ++i) {
    int g = i & (NG - 1), b = i >> 3;
    if (g == 0) boff[b] = run;
    bcur[g * nb + b] = run;
    run += bhist[g * nb + b];
  }
  if (t == 255) boff[nb] = E;
}

__global__ void bscatter_kernel(const int* __restrict__ src, const int* __restrict__ dst,
                                int E, int nb, int* __restrict__ bcur,
                                int2* __restrict__ tmp) {
  int e = blockIdx.x * blockDim.x + threadIdx.x;
  int g = blockIdx.x & (NG - 1);
  if (e < E) {
    int d = dst[e];
    int p = atomicAdd(&bcur[g * nb + (d >> BSH)], 1);
    tmp[p] = make_int2(src[e], d);
  }
}

__global__ void bbuild_kernel(const int2* __restrict__ tmp, const int* __restrict__ boff,
                              int nb, int N, int E, int* __restrict__ row_ptr,
                              int* __restrict__ cols, float* __restrict__ dinv) {
  __shared__ int ldeg[BSZ];
  __shared__ int lcur[BSZ];
  int b = blockIdx.x;
  int node0 = b << BSH;
  int t = threadIdx.x;
  int beg = boff[b], end = boff[b + 1];
  if (t < BSZ) ldeg[t] = 0;
  __syncthreads();
  for (int i = beg + t; i < end; i += blockDim.x) {
    atomicAdd(&ldeg[tmp[i].y - node0], 1);
  }
  __syncthreads();
  if (t == 0) {
    int run = beg;
    int nn = min(BSZ, N - node0);
    for (int j = 0; j < nn; ++j) {
      lcur[j] = run;
      row_ptr[node0 + j] = run;
      dinv[node0 + j] = rsqrtf((float)ldeg[j] + 1.0f);
      run += ldeg[j];
    }
    if (b == nb - 1) row_ptr[N] = E;
  }
  __syncthreads();
  for (int i = beg + t; i < end; i += blockDim.x) {
    int2 eg = tmp[i];
    int p = atomicAdd(&lcur[eg.y - node0], 1);
    cols[p] = eg.x;
  }
}

// ---------------- W split+fragment prep ----------------
// B-fragment for mfma_f32_16x16x32_bf16: lane holds B[k][col], col = ct*16 + (lane&15),
// k = ks*32 + (lane>>4)*8 + j, j=0..7 packed pairwise (even j in low 16 bits).

__global__ void wsplit_kernel(const float* __restrict__ W, uint4* __restrict__ hi4,
                              uint4* __restrict__ lo4) {
  int tid = blockIdx.x * blockDim.x + threadIdx.x;  // 2048 total
  int lane = tid & 63;
  int ks = (tid >> 6) & 3;
  int ct = tid >> 8;
  int col = ct * 16 + (lane & 15);
  int k0 = ks * 32 + ((lane >> 4) << 3);
  uint32 h[8], l[8];
#pragma unroll
  for (int j = 0; j < 8; ++j) {
    float w = W[(size_t)(k0 + j) * DIM + col];
    uint32 hh = bf16_rtne(w);
    float rem = w - bf16_to_f(hh);
    l[j] = bf16_rtne(rem);
    h[j] = hh;
  }
  uint4 H, L;
  H.x = h[0] | (h[1] << 16); H.y = h[2] | (h[3] << 16);
  H.z = h[4] | (h[5] << 16); H.w = h[6] | (h[7] << 16);
  L.x = l[0] | (l[1] << 16); L.y = l[2] | (l[3] << 16);
  L.z = l[4] | (l[5] << 16); L.w = l[6] | (l[7] << 16);
  hi4[tid] = H;
  lo4[tid] = L;
}

// ---------------- split-bf16 MFMA GEMM ----------------
// outb[n,128] (packed bf16) = act( (in[n,128] @ W) * rowscale + bias )

__launch_bounds__(256, 3)
__global__ void gemm_mfma_kernel(const float* __restrict__ in, const uint4* __restrict__ wHi,
                                 const uint4* __restrict__ wLo, uint32* __restrict__ outb,
                                 int n, const float* __restrict__ rowscale,
                                 const float* __restrict__ bias, float slope) {
  __shared__ unsigned short sA[2 * 64 * 128];  // hi | lo, XOR-swizzled rows
  __shared__ unsigned short sO[64 * 128];
  int t = threadIdx.x;
  int row0 = blockIdx.x * 64;

  // stage A, split into hi/lo bf16
  {
    int quad = t & 31;   // float4 within row
    int r = t >> 5;      // 0..7
#pragma unroll
    for (int i = 0; i < 8; ++i) {
      int row = r + i * 8;
      int grow = row0 + row;
      float4 v = make_float4(0.f, 0.f, 0.f, 0.f);
      if (grow < n) v = *(const float4*)(in + (size_t)grow * DIM + quad * 4);
      uint32 h0 = bf16_rtne(v.x), h1 = bf16_rtne(v.y), h2 = bf16_rtne(v.z), h3 = bf16_rtne(v.w);
      uint32 l0 = bf16_rtne(v.x - bf16_to_f(h0));
      uint32 l1 = bf16_rtne(v.y - bf16_to_f(h1));
      uint32 l2 = bf16_rtne(v.z - bf16_to_f(h2));
      uint32 l3 = bf16_rtne(v.w - bf16_to_f(h3));
      int sidx = (row * 128 + quad * 4) ^ ((row & 7) << 3);
      *(uint2*)&sA[sidx] = make_uint2(h0 | (h1 << 16), h2 | (h3 << 16));
      *(uint2*)&sA[64 * 128 + sidx] = make_uint2(l0 | (l1 << 16), l2 | (l3 << 16));
    }
  }
  __syncthreads();

  int lane = t & 63;
  int w = t >> 6;        // wave 0..3 -> rows w*16..w*16+15
  int rbase = w * 16;
  f32x4 acc[8];
#pragma unroll
  for (int ct = 0; ct < 8; ++ct) acc[ct] = (f32x4){0.f, 0.f, 0.f, 0.f};

  int fragRow = rbase + (lane & 15);
  int fragSwz = (fragRow & 7) << 3;
#pragma unroll
  for (int ks = 0; ks < 4; ++ks) {
    int cidx = ks * 32 + ((lane >> 4) << 3);
    int sidx = (fragRow * 128 + cidx) ^ fragSwz;
    uint4 au = *(uint4*)&sA[sidx];
    uint4 alu = *(uint4*)&sA[64 * 128 + sidx];
    short8 ah = __builtin_bit_cast(short8, au);
    short8 al = __builtin_bit_cast(short8, alu);
#pragma unroll
    for (int ct = 0; ct < 8; ++ct) {
      int widx = (ct * 4 + ks) * 64 + lane;
      short8 bh = __builtin_bit_cast(short8, wHi[widx]);
      short8 bl = __builtin_bit_cast(short8, wLo[widx]);
      acc[ct] = __builtin_amdgcn_mfma_f32_16x16x32_bf16(al, bh, acc[ct], 0, 0, 0);
      acc[ct] = __builtin_amdgcn_mfma_f32_16x16x32_bf16(ah, bl, acc[ct], 0, 0, 0);
      acc[ct] = __builtin_amdgcn_mfma_f32_16x16x32_bf16(ah, bh, acc[ct], 0, 0, 0);
    }
  }

  // epilogue: scale/bias/act, pack bf16 into sO (swizzled), then coalesced store
  float rs[4];
#pragma unroll
  for (int r = 0; r < 4; ++r) {
    int grow = row0 + rbase + ((lane >> 4) << 2) + r;
    rs[r] = rowscale ? ((grow < n) ? rowscale[grow] : 0.f) : 1.0f;
  }
#pragma unroll
  for (int ct = 0; ct < 8; ++ct) {
    int col = ct * 16 + (lane & 15);
    float bv = bias ? bias[col] : 0.f;
#pragma unroll
    for (int r = 0; r < 4; ++r) {
      int rowL = rbase + ((lane >> 4) << 2) + r;
      float v = acc[ct][r] * rs[r] + bv;
      v = (v > 0.f) ? v : v * slope;
      int sidx = (rowL * 128 + col) ^ ((rowL & 7) << 3);
      sO[sidx] = (unsigned short)bf16_rtne(v);
    }
  }
  __syncthreads();
#pragma unroll
  for (int it = 0; it < 4; ++it) {
    int s = it * 64 + lane;          // 0..255 slots of 8 ushorts within this wave's 16 rows
    int row = rbase + (s >> 4);
    int sin = s & 15;
    int sidx = row * 128 + ((sin * 8) ^ ((row & 7) << 3));
    uint4 v = *(uint4*)&sO[sidx];
    int grow = row0 + row;
    if (grow < n) *(uint4*)(outb + (size_t)grow * 64 + sin * 4) = v;
  }
}

// ---------------- GCN aggregation (bf16 gather, fp32 out) ----------------

__launch_bounds__(256)
__global__ void agg_kernel(const uint32* __restrict__ g, const int* __restrict__ row_ptr,
                           const int* __restrict__ cols, const float* __restrict__ dinv,
                           const float* __restrict__ bias, float* __restrict__ out,
                           int n, int relu) {
  int lane = threadIdx.x & 63;
  int node = (blockIdx.x * blockDim.x + threadIdx.x) >> 6;
  if (node >= n) return;
  int beg = row_ptr[node];
  int end = row_ptr[node + 1];
  float ax, ay;
  unpack2(g[(size_t)node * 64 + lane], ax, ay);
  int e = beg;
  for (; e + 4 <= end; e += 4) {
    int s0 = cols[e + 0], s1 = cols[e + 1], s2 = cols[e + 2], s3 = cols[e + 3];
    uint32 u0 = g[(size_t)s0 * 64 + lane];
    uint32 u1 = g[(size_t)s1 * 64 + lane];
    uint32 u2 = g[(size_t)s2 * 64 + lane];
    uint32 u3 = g[(size_t)s3 * 64 + lane];
    float x0, y0, x1, y1, x2, y2, x3, y3;
    unpack2(u0, x0, y0); unpack2(u1, x1, y1);
    unpack2(u2, x2, y2); unpack2(u3, x3, y3);
    ax += (x0 + x1) + (x2 + x3);
    ay += (y0 + y1) + (y2 + y3);
  }
  for (; e < end; ++e) {
    uint32 u0 = g[(size_t)cols[e] * 64 + lane];
    float x0, y0;
    unpack2(u0, x0, y0);
    ax += x0;
    ay += y0;
  }
  float di = dinv[node];
  float2 bv = ((const float2*)bias)[lane];
  float ox = fmaf(di, ax, bv.x);
  float oy = fmaf(di, ay, bv.y);
  if (relu) {
    ox = fmaxf(ox, 0.f);
    oy = fmaxf(oy, 0.f);
  }
  ((float2*)out)[(size_t)node * 64 + lane] = make_float2(ox, oy);
}

// ---------------- heads ----------------

__global__ void twocol_f32_kernel(const float* __restrict__ Z, const float* __restrict__ Wc,
                                  const float* __restrict__ bc, float* __restrict__ out,
                                  int n, float slope) {
  int lane = threadIdx.x & 63;
  int wid = (blockIdx.x * blockDim.x + threadIdx.x) >> 6;
  int nw = (gridDim.x * blockDim.x) >> 6;
  float w00 = Wc[(2 * lane) * 2 + 0];
  float w01 = Wc[(2 * lane) * 2 + 1];
  float w10 = Wc[(2 * lane + 1) * 2 + 0];
  float w11 = Wc[(2 * lane + 1) * 2 + 1];
  float b0 = bc[0], b1 = bc[1];
  for (int i = wid; i < n; i += nw) {
    float2 z = ((const float2*)Z)[(size_t)i * 64 + lane];
    float p0 = z.x * w00 + z.y * w10;
    float p1 = z.x * w01 + z.y * w11;
#pragma unroll
    for (int off = 32; off; off >>= 1) {
      p0 += __shfl_xor(p0, off);
      p1 += __shfl_xor(p1, off);
    }
    if (lane == 0) {
      float o0 = p0 + b0, o1 = p1 + b1;
      out[2 * (size_t)i + 0] = (o0 > 0.f) ? o0 : slope * o0;
      out[2 * (size_t)i + 1] = (o1 > 0.f) ? o1 : slope * o1;
    }
  }
}

__global__ void twocol_bf16_kernel(const uint32* __restrict__ Z, const float* __restrict__ Wc,
                                   const float* __restrict__ bc, float* __restrict__ out,
                                   int n, float slope) {
  int lane = threadIdx.x & 63;
  int wid = (blockIdx.x * blockDim.x + threadIdx.x) >> 6;
  int nw = (gridDim.x * blockDim.x) >> 6;
  float w00 = Wc[(2 * lane) * 2 + 0];
  float w01 = Wc[(2 * lane) * 2 + 1];
  float w10 = Wc[(2 * lane + 1) * 2 + 0];
  float w11 = Wc[(2 * lane + 1) * 2 + 1];
  float b0 = bc[0], b1 = bc[1];
  for (int i = wid; i < n; i += nw) {
    float zx, zy;
    unpack2(Z[(size_t)i * 64 + lane], zx, zy);
    float p0 = zx * w00 + zy * w10;
    float p1 = zx * w01 + zy * w11;
#pragma unroll
    for (int off = 32; off; off >>= 1) {
      p0 += __shfl_xor(p0, off);
      p1 += __shfl_xor(p1, off);
    }
    if (lane == 0) {
      float o0 = p0 + b0, o1 = p1 + b1;
      out[2 * (size_t)i + 0] = (o0 > 0.f) ? o0 : slope * o0;
      out[2 * (size_t)i + 1] = (o1 > 0.f) ? o1 : slope * o1;
    }
  }
}

__global__ void ydot_kernel(const float* __restrict__ Z, const int* __restrict__ idx,
                            const float* __restrict__ w, const float* __restrict__ b,
                            float* __restrict__ out, int T) {
  int lane = threadIdx.x & 63;
  int t = (blockIdx.x * blockDim.x + threadIdx.x) >> 6;
  if (t >= T) return;
  float2 wv = ((const float2*)w)[lane];
  int node = idx[t];
  float2 z = ((const float2*)Z)[(size_t)node * 64 + lane];
  float pp = z.x * wv.x + z.y * wv.y;
#pragma unroll
  for (int off = 32; off; off >>= 1) pp += __shfl_xor(pp, off);
  if (lane == 0) {
    float o = pp + b[0];
    out[t] = (o > 0.f) ? o : 0.01f * o;
  }
}

// ---------------- launch ----------------

extern "C" void kernel_launch(void* const* d_in, const int* in_sizes, int n_in,
                              void* d_out, int out_size, void* d_ws, size_t ws_size,
                              hipStream_t stream) {
  const int N = in_sizes[0] / DIM;
  const int E = in_sizes[1] / 2;
  const int T = in_sizes[4];
  const int nb = (N + BSZ - 1) >> BSH;

  const float* x = (const float*)d_in[0];
  const int* ei = (const int*)d_in[1];
  const float* fx = (const float*)d_in[2];
  const int* fei = (const int*)d_in[3];
  const int* treat = (const int*)d_in[4];
  const int* control = (const int*)d_in[5];
  const float* W1 = (const float*)d_in[6];
  const float* b1 = (const float*)d_in[7];
  const float* W2 = (const float*)d_in[8];
  const float* b2 = (const float*)d_in[9];
  const float* Wy1 = (const float*)d_in[10];
  const float* by1 = (const float*)d_in[11];
  const float* Wy0 = (const float*)d_in[12];
  const float* by0 = (const float*)d_in[13];
  const float* Wb = (const float*)d_in[14];
  const float* bb = (const float*)d_in[15];
  const float* Wp1 = (const float*)d_in[16];
  const float* bp1 = (const float*)d_in[17];
  const float* Wp2 = (const float*)d_in[18];
  const float* bp2 = (const float*)d_in[19];

  float* out = (float*)d_out;

  // workspace layout (~91 MB)
  char* p = (char*)d_ws;
  float* bufZ = (float*)p;   p += (size_t)N * DIM * sizeof(float);        // 51.2 MB (fp32 Z; aliased by tmp during CSR build)
  uint32* bufG = (uint32*)p; p += (size_t)N * (DIM / 2) * sizeof(uint32); // 25.6 MB (bf16 rows)
  int* row_ptr = (int*)p;    p += (size_t)(N + 16) * sizeof(int);
  float* dinv = (float*)p;   p += (size_t)(N + 16) * sizeof(float);
  int* cols = (int*)p;       p += (size_t)E * sizeof(int);
  int* bhist = (int*)p;      p += (size_t)nb * NG * sizeof(int);
  int* bcur = (int*)p;       p += (size_t)nb * NG * sizeof(int);
  int* boff = (int*)p;       p += (size_t)(nb + 2) * sizeof(int);
  uint4* w1Hi = (uint4*)p;   p += 2048 * sizeof(uint4);
  uint4* w1Lo = (uint4*)p;   p += 2048 * sizeof(uint4);
  uint4* w2Hi = (uint4*)p;   p += 2048 * sizeof(uint4);
  uint4* w2Lo = (uint4*)p;   p += 2048 * sizeof(uint4);
  uint4* wp1Hi = (uint4*)p;  p += 2048 * sizeof(uint4);
  uint4* wp1Lo = (uint4*)p;  p += 2048 * sizeof(uint4);
  int2* tmp = (int2*)bufZ;   // CSR staging aliases bufZ

  float* oy1 = out;
  float* oyc0 = out + T;
  float* oy0 = out + 2 * T;
  float* oyc1 = out + 3 * T;
  float* ofp = out + 4 * T;
  float* ofpf = out + 4 * T + 2 * N;
  float* otp = out + 4 * T + 4 * N;
  float* otpf = out + 4 * T + 6 * N;

  // W fragment prep (shared by both graphs)
  wsplit_kernel<<<8, 256, 0, stream>>>(W1, w1Hi, w1Lo);
  wsplit_kernel<<<8, 256, 0, stream>>>(W2, w2Hi, w2Lo);
  wsplit_kernel<<<8, 256, 0, stream>>>(Wp1, wp1Hi, wp1Lo);

  auto run = [&](const float* X, const int* EI,
                 float* y_t, const float* Wt, const float* bt,
                 float* y_c, const float* Wc, const float* bc,
                 float* fp, float* tp) {
    const int* srcp = EI;
    const int* dstp = EI + E;
    // XCD-partitioned bucketed CSR build
    hipMemsetAsync(bhist, 0, (size_t)nb * NG * sizeof(int), stream);
    bhist_kernel<<<(E + 255) / 256, 256, 0, stream>>>(dstp, E, nb, bhist);
    bscan_kernel<<<1, 256, 0, stream>>>(bhist, nb, E, boff, bcur);
    bscatter_kernel<<<(E + 255) / 256, 256, 0, stream>>>(srcp, dstp, E, nb, bcur, tmp);
    bbuild_kernel<<<nb, 256, 0, stream>>>(tmp, boff, nb, N, E, row_ptr, cols, dinv);
    // layer 1: g = (X@W1)*dinv (bf16) ; Z1 = relu(dinv*(sum g + g_self) + b1)
    gemm_mfma_kernel<<<(N + 63) / 64, 256, 0, stream>>>(X, w1Hi, w1Lo, bufG, N, dinv, nullptr, 1.0f);
    agg_kernel<<<(N + 3) / 4, 256, 0, stream>>>(bufG, row_ptr, cols, dinv, b1, bufZ, N, 1);
    // layer 2
    gemm_mfma_kernel<<<(N + 63) / 64, 256, 0, stream>>>(bufZ, w2Hi, w2Lo, bufG, N, dinv, nullptr, 1.0f);
    agg_kernel<<<(N + 3) / 4, 256, 0, stream>>>(bufG, row_ptr, cols, dinv, b2, bufZ, N, 0);
    // bufZ = Z2 (fp32)
    // tprob: P1 = lrelu(Z2@Wp1 + bp1) (bf16); tp = lrelu(P1@Wp2 + bp2)
    gemm_mfma_kernel<<<(N + 63) / 64, 256, 0, stream>>>(bufZ, wp1Hi, wp1Lo, bufG, N, nullptr, bp1, 0.01f);
    twocol_bf16_kernel<<<2048, 256, 0, stream>>>(bufG, Wp2, bp2, tp, N, 0.01f);
    twocol_f32_kernel<<<2048, 256, 0, stream>>>(bufZ, Wb, bb, fp, N, 1.0f);
    ydot_kernel<<<(T + 3) / 4, 256, 0, stream>>>(bufZ, treat, Wt, bt, y_t, T);
    ydot_kernel<<<(T + 3) / 4, 256, 0, stream>>>(bufZ, control, Wc, bc, y_c, T);
  };

  run(x, ei, oy1, Wy1, by1, oy0, Wy0, by0, ofp, otp);
  run(fx, fei, oyc0, Wy0, by0, oyc1, Wy1, by1, ofpf, otpf);
}